// Round 1
// baseline (406.375 us; speedup 1.0000x reference)
//
#include <hip/hip_runtime.h>
#include <math.h>

#define NB    64
#define NS    4096
#define NHQ   32
#define NHKV  8
#define ND    128
#define NG    4            // NHQ / NHKV
#define WAVES 8
#define NTHREADS (WAVES*64)

// exact fp32 -> e4m3fn (RNE, clip +-448) returned as fp32
__device__ __forceinline__ float quant_e4m3(float x) {
    float a = fabsf(x);
    a = fminf(a, 448.0f);
    unsigned ui = __float_as_uint(a);
    int e  = (int)(ui >> 23) - 127;          // a==0 -> e=-127, handled below
    int se = (e < -6 ? -6 : e) - 3;          // step exponent (denormal step = 2^-9)
    float stp = __uint_as_float((unsigned)(se + 127) << 23);
    float qv  = rintf(a / stp) * stp;        // a/stp exact (stp is pow2), rintf = RNE
    return copysignf(qv, x);
}

__global__ __launch_bounds__(NTHREADS, 4) void attn_decode_quant(
    const float* __restrict__ qin,
    const float* __restrict__ kc,
    const float* __restrict__ vc,
    const float* __restrict__ qscale,
    float* __restrict__ out)
{
    __shared__ double s_acc[WAVES][NG][ND];   // 32 KB
    __shared__ double s_l[WAVES][NG];
    __shared__ float  s_m[WAVES][NG];
    __shared__ double s_w[WAVES][NG];
    __shared__ double s_lt[NG];

    const int bh   = blockIdx.x;          // 0..511
    const int b    = bh >> 3;
    const int h    = bh & 7;
    const int tid  = threadIdx.x;
    const int wave = tid >> 6;
    const int lane = tid & 63;
    const int half = lane >> 5;
    const int l32  = lane & 31;

    // replicate reference: 1.0 / np.sqrt(128).astype(np.float32), applied as f32 mul
    const float sm_scale = (float)(1.0 / (double)sqrtf(128.0f));

    // q fragments: q[b, h*G+g, l32*4 .. +3]
    float4 qf[NG];
    {
        const float* qb = qin + ((size_t)b * NHQ + (size_t)h * NG) * ND + l32 * 4;
        #pragma unroll
        for (int g = 0; g < NG; ++g) qf[g] = *(const float4*)(qb + g * ND);
    }

    const size_t rs = (size_t)NHKV * ND;  // 1024 floats between consecutive s
    const float* kb = kc + ((size_t)b * NS * NHKV + h) * ND;
    const float* vb = vc + ((size_t)b * NS * NHKV + h) * ND;

    const int s0  = wave * (NS / WAVES) + half;   // this lane-half's first row
    const int NIT = (NS / WAVES) / 2;             // 256 iters, 2 keys/iter/wave

    const float* kp = kb + (size_t)s0 * rs + l32 * 4;
    const float* vp = vb + (size_t)s0 * rs + l32 * 4;

    float  m[NG];
    double l[NG];
    double acc[NG][4];
    #pragma unroll
    for (int g = 0; g < NG; ++g) {
        m[g] = -INFINITY; l[g] = 0.0;
        #pragma unroll
        for (int j = 0; j < 4; ++j) acc[g][j] = 0.0;
    }

    // 2-deep software pipeline
    float4 ka  = *(const float4*)(kp);
    float4 va  = *(const float4*)(vp);
    float4 kn  = *(const float4*)(kp + 2 * rs);
    float4 vn  = *(const float4*)(vp + 2 * rs);

    for (int i = 0; i < NIT; ++i) {
        float4 kf = ka, vf = va;
        ka = kn; va = vn;
        int ip = (i + 2 < NIT) ? (i + 2) : (NIT - 1);   // clamp: harmless re-read
        kn = *(const float4*)(kp + (size_t)ip * 2 * rs);
        vn = *(const float4*)(vp + (size_t)ip * 2 * rs);

        float sg[NG];
        #pragma unroll
        for (int g = 0; g < NG; ++g) {
            float s = qf[g].x * kf.x;
            s = fmaf(qf[g].y, kf.y, s);
            s = fmaf(qf[g].z, kf.z, s);
            s = fmaf(qf[g].w, kf.w, s);
            sg[g] = s;
        }
        #pragma unroll
        for (int g = 0; g < NG; ++g) {
            #pragma unroll
            for (int mask = 1; mask < 32; mask <<= 1)
                sg[g] += __shfl_xor(sg[g], mask);
        }

        double v0d = (double)vf.x, v1d = (double)vf.y;
        double v2d = (double)vf.z, v3d = (double)vf.w;

        #pragma unroll
        for (int g = 0; g < NG; ++g) {
            float s = sg[g] * sm_scale;
            float p;
            if (s > m[g]) {                    // rare (running-max record), uniform per half
                double corr = exp((double)(m[g] - s));   // exp(-inf)=0 on first hit
                l[g] *= corr;
                acc[g][0] *= corr; acc[g][1] *= corr;
                acc[g][2] *= corr; acc[g][3] *= corr;
                m[g] = s;
                p = 1.0f;
            } else {
                p = expf(s - m[g]);            // fp32 exp, matches numpy softmax path
            }
            double pd = (double)p;
            l[g] += pd;
            acc[g][0] = fma(pd, v0d, acc[g][0]);
            acc[g][1] = fma(pd, v1d, acc[g][1]);
            acc[g][2] = fma(pd, v2d, acc[g][2]);
            acc[g][3] = fma(pd, v3d, acc[g][3]);
        }
    }

    // merge the two half-wave partials (lane ^ 32)
    #pragma unroll
    for (int g = 0; g < NG; ++g) {
        float  mo = __shfl_xor(m[g], 32);
        double lo = __shfl_xor(l[g], 32);
        double a0 = __shfl_xor(acc[g][0], 32);
        double a1 = __shfl_xor(acc[g][1], 32);
        double a2 = __shfl_xor(acc[g][2], 32);
        double a3 = __shfl_xor(acc[g][3], 32);
        float M2 = fmaxf(m[g], mo);
        double w  = exp((double)(m[g] - M2));
        double wo = exp((double)(mo   - M2));
        acc[g][0] = acc[g][0] * w + a0 * wo;
        acc[g][1] = acc[g][1] * w + a1 * wo;
        acc[g][2] = acc[g][2] * w + a2 * wo;
        acc[g][3] = acc[g][3] * w + a3 * wo;
        l[g] = l[g] * w + lo * wo;
        m[g] = M2;
    }

    if (half == 0) {
        #pragma unroll
        for (int g = 0; g < NG; ++g) {
            #pragma unroll
            for (int j = 0; j < 4; ++j)
                s_acc[wave][g][l32 * 4 + j] = acc[g][j];
        }
        if (l32 == 0) {
            #pragma unroll
            for (int g = 0; g < NG; ++g) { s_m[wave][g] = m[g]; s_l[wave][g] = l[g]; }
        }
    }
    __syncthreads();

    // per-g global max + weights + denominator
    if (tid < NG) {
        int g = tid;
        float M = -INFINITY;
        for (int pa = 0; pa < WAVES; ++pa) M = fmaxf(M, s_m[pa][g]);
        double ltot = 0.0;
        for (int pa = 0; pa < WAVES; ++pa) {
            double w = exp((double)(s_m[pa][g] - M));
            s_w[pa][g] = w;
            ltot += s_l[pa][g] * w;
        }
        s_lt[g] = ltot;
    }
    __syncthreads();

    // 512 outputs, 512 threads: (g,d)
    {
        const float qs = qscale[0];
        int g = tid >> 7;
        int d = tid & 127;
        double o = 0.0;
        for (int pa = 0; pa < WAVES; ++pa)
            o += s_acc[pa][g][d] * s_w[pa][g];
        o /= s_lt[g];
        float x = (float)o;
        x = x / qs;
        out[((size_t)b * NHQ + (size_t)(h * NG + g)) * ND + d] = quant_e4m3(x);
    }
}

extern "C" void kernel_launch(void* const* d_in, const int* in_sizes, int n_in,
                              void* d_out, int out_size, void* d_ws, size_t ws_size,
                              hipStream_t stream) {
    (void)in_sizes; (void)n_in; (void)d_ws; (void)ws_size; (void)out_size;
    const float* q  = (const float*)d_in[0];
    const float* k  = (const float*)d_in[1];
    const float* v  = (const float*)d_in[2];
    const float* qs = (const float*)d_in[3];
    float* o = (float*)d_out;
    hipLaunchKernelGGL(attn_decode_quant, dim3(NB * NHKV), dim3(NTHREADS), 0, stream,
                       q, k, v, qs, o);
}